// Round 5
// baseline (159.044 us; speedup 1.0000x reference)
//
#include <hip/hip_runtime.h>

#define BN_EPS 1e-5f
#define QR_IMG   73984      // 34*34*64 bytes per (kc, image)
#define QR_KC    2367488    // 32 * QR_IMG
#define SR_STEP  16384      // per (t,kc): 256 o * 64B

typedef __attribute__((ext_vector_type(4))) int int32x4;

// ---------------------------------------------------------------------------
// Weight prep: alpha[o] = mean|w[o]| ; Sr[(t*4+kc)*256 + o][64] = sign i8.
// ---------------------------------------------------------------------------
__global__ void prep_w_kernel(const float* __restrict__ w,
                              signed char* __restrict__ Sr,
                              float* __restrict__ alpha) {
    int o = blockIdx.x;   // 256
    int c = threadIdx.x;  // 256
    const float* wp = w + (o * 256 + c) * 9;
    float s = 0.f;
    __shared__ __align__(16) signed char lsg[9][256];
    __shared__ float red[256];
#pragma unroll
    for (int j = 0; j < 9; ++j) {
        float v = wp[j];
        s += fabsf(v);
        lsg[j][c] = v > 0.f ? 1 : (v < 0.f ? -1 : 0);
    }
    red[c] = s;
    __syncthreads();
    for (int off = 128; off > 0; off >>= 1) {
        if (c < off) red[c] += red[c + off];
        __syncthreads();
    }
    if (c == 0) alpha[o] = red[0] / 2304.0f;
    if (c < 144) {
        int t = c / 16, u = c % 16;
        int c0 = u * 16;
        int kc = c0 >> 6, cb = c0 & 63;
        int32x4 v = *(const int32x4*)(&lsg[t][c0]);
        *(int32x4*)(Sr + (size_t)((t * 4 + kc) * 256 + o) * 64 + cb) = v;
    }
}

// ---------------------------------------------------------------------------
// Zero halo slots of both q buffers: border (y,x) of each [34][34] plane.
// 2 buf * 4 kc * 32 n * 132 slots * 4 sub = 135168 threads = 528 * 256.
// ---------------------------------------------------------------------------
__global__ void halo_zero_kernel(signed char* __restrict__ qr1,
                                 signed char* __restrict__ qr2) {
    int idx = blockIdx.x * 256 + threadIdx.x;
    int sub = idx & 3;
    int rest = idx >> 2;        // 33792
    int s = rest % 132;
    int r2 = rest / 132;        // 0..255 = 2 buf * 4 kc * 32 n
    int n = r2 & 31;
    int kc = (r2 >> 5) & 3;
    int b = r2 >> 7;
    int r, cc;
    if (s < 34)       { r = 0;        cc = s; }
    else if (s < 68)  { r = 33;       cc = s - 34; }
    else if (s < 100) { r = s - 67;   cc = 0; }
    else              { r = s - 99;   cc = 33; }
    signed char* p = (b ? qr2 : qr1) + (size_t)kc * QR_KC + (size_t)n * QR_IMG +
                     (size_t)(r * 34 + cc) * 64 + sub * 16;
    int32x4 z; z[0] = 0; z[1] = 0; z[2] = 0; z[3] = 0;
    *(int32x4*)p = z;
}

// ---------------------------------------------------------------------------
// partials[bid] = block-sum of |bn1(x)| (deterministic tree).
// ---------------------------------------------------------------------------
__global__ void bnabs_reduce_kernel(const float* __restrict__ x,
                                    const float* __restrict__ gamma,
                                    const float* __restrict__ beta,
                                    const float* __restrict__ mean,
                                    const float* __restrict__ var,
                                    float* __restrict__ partials) {
    int tid = blockIdx.x * blockDim.x + threadIdx.x;
    int nthreads = gridDim.x * blockDim.x;
    const float4* x4 = (const float4*)x;
    float s = 0.f;
    for (int i = tid; i < 2097152; i += nthreads) {
        int c = (i >> 8) & 255;
        float inv = gamma[c] * rsqrtf(var[c] + BN_EPS);
        float b = beta[c] - mean[c] * inv;
        float4 v = x4[i];
        s += fabsf(v.x * inv + b) + fabsf(v.y * inv + b) +
             fabsf(v.z * inv + b) + fabsf(v.w * inv + b);
    }
    __shared__ float red[256];
    red[threadIdx.x] = s;
    __syncthreads();
    for (int off = 128; off > 0; off >>= 1) {
        if (threadIdx.x < off) red[threadIdx.x] += red[threadIdx.x + off];
        __syncthreads();
    }
    if (threadIdx.x == 0) partials[blockIdx.x] = red[0];
}

__global__ void finalize_delta_kernel(const float* __restrict__ partials, int n,
                                      float scale, float* __restrict__ out) {
    __shared__ float red[256];
    float s = 0.f;
    for (int i = threadIdx.x; i < n; i += 256) s += partials[i];
    red[threadIdx.x] = s;
    __syncthreads();
    for (int off = 128; off > 0; off >>= 1) {
        if (threadIdx.x < off) red[threadIdx.x] += red[threadIdx.x + off];
        __syncthreads();
    }
    if (threadIdx.x == 0) *out = red[0] * scale;
}

// ---------------------------------------------------------------------------
// Quantize into k-chunk-major padded layout:
// qr[kc][n][y+1][x+1][64] i8 in {-1,0,+1}; halo untouched (zeroed once).
// ---------------------------------------------------------------------------
__global__ __launch_bounds__(256) void quant_kernel(
    const float* __restrict__ src,
    const float* __restrict__ gamma, const float* __restrict__ beta,
    const float* __restrict__ mean, const float* __restrict__ var,
    const float* __restrict__ deltaPtr, signed char* __restrict__ qr) {
    __shared__ float sInv[256], sB[256];
    int tid = threadIdx.x;
    {
        float inv = gamma[tid] * rsqrtf(var[tid] + BN_EPS);
        sInv[tid] = inv;
        sB[tid] = beta[tid] - mean[tid] * inv;
    }
    __syncthreads();
    int bid = blockIdx.x;          // 512 = 32 n * 16 pblk
    int n = bid >> 4;
    int p0 = (bid & 15) * 64;
    int l = tid & 63, wv = tid >> 6;   // wv == kc
    int p = p0 + l;
    int y = p >> 5, x = p & 31;
    float delta = *deltaPtr;
    const float* sp = src + (size_t)n * 262144 + p;
    signed char* qp = qr + (size_t)wv * QR_KC + (size_t)n * QR_IMG +
                      (size_t)((y + 1) * 34 + (x + 1)) * 64;
#pragma unroll
    for (int kg = 0; kg < 4; ++kg) {
        int w4[4];
#pragma unroll
        for (int d = 0; d < 4; ++d) {
            int wrd = 0;
#pragma unroll
            for (int j = 0; j < 4; ++j) {
                int c = wv * 64 + kg * 16 + d * 4 + j;
                float s = sp[c * 1024] * sInv[c] + sB[c];
                int qv = s > delta ? 1 : (s < -delta ? -1 : 0);
                wrd |= (qv & 255) << (8 * j);
            }
            w4[d] = wrd;
        }
        int32x4 vv;
        vv[0] = w4[0]; vv[1] = w4[1]; vv[2] = w4[2]; vv[3] = w4[3];
        *(int32x4*)(qp + kg * 16) = vv;
    }
}

// ---------------------------------------------------------------------------
// TBN conv: i8 MFMA 16x16x64. 1024 blocks x 4 waves; block tile 64o x 128px,
// wave tile 32o x 64px. Inline-asm global loads + counted vmcnt(6) pipeline
// (compiler cannot collapse: volatile order + WAR on ping-pong regs).
// ---------------------------------------------------------------------------
template <bool FUSE>
__global__ __launch_bounds__(256, 4) void tbn_conv_kernel(
    const signed char* __restrict__ qr,   // [4][32][34][34][64] i8
    const signed char* __restrict__ Sr,   // [36][256][64] i8
    const float* __restrict__ alpha,      // [256]
    const float* __restrict__ resid,      // [32][256][1024] f32
    float* __restrict__ out,              // [32][256][1024] f32
    const float* __restrict__ gamma, const float* __restrict__ beta,
    const float* __restrict__ mean, const float* __restrict__ var,
    float* __restrict__ partials) {
    int bid = blockIdx.x;
    int wg = (bid & 7) * 128 + (bid >> 3);  // bijective, 1024 % 8 == 0
    int n = wg >> 5;
    int pb = (wg >> 2) & 7;
    int ob = wg & 3;
    int tid = threadIdx.x, lane = tid & 63, wid = tid >> 6;
    int l15 = lane & 15, kg = lane >> 4;

    __shared__ float sAl[64], sInvS[64], sBS[64];
    __shared__ float red[256];
    if (tid < 64) {
        int o = ob * 64 + tid;
        sAl[tid] = alpha[o];
        if (FUSE) {
            float inv = gamma[o] * rsqrtf(var[o] + BN_EPS);
            sInvS[tid] = inv;
            sBS[tid] = beta[o] - mean[o] * inv;
        }
    }
    __syncthreads();

    int oW = (wid >> 1) * 32, pW = (wid & 1) * 64;
    int o0 = ob * 64 + oW;

    const signed char* Abase = Sr + (size_t)(o0 + l15) * 64 + kg * 16;
    const signed char* Bbase = qr + (size_t)n * QR_IMG + kg * 16;
    int bOff[4], pL[4];
#pragma unroll
    for (int nn = 0; nn < 4; ++nn) {
        int p = pb * 128 + pW + nn * 16 + l15;
        pL[nn] = p;
        int pt = p - l15;               // tile origin, multiple of 16
        int y = pt >> 5, x = pt & 31;   // all 16 lanes share y
        bOff[nn] = ((y + 1) * 34 + (x + 1) + l15) * 64;
    }

    int32x4 acc[2][4];
#pragma unroll
    for (int m = 0; m < 2; ++m)
#pragma unroll
        for (int nn = 0; nn < 4; ++nn) {
            acc[m][nn][0] = 0; acc[m][nn][1] = 0;
            acc[m][nn][2] = 0; acc[m][nn][3] = 0;
        }

    int32x4 fa[2][2], fb[2][4];

#define GLD(D, P) \
    asm volatile("global_load_dwordx4 %0, %1, off" : "=v"(D) : "v"(P))

#define LOADS(I, PAR)                                                         \
    do {                                                                      \
        const int t_ = (I) >> 2, kc_ = (I) & 3;                               \
        const int kh_ = t_ / 3 - 1, kw_ = t_ % 3 - 1;                         \
        const signed char* pa_ = Abase + (size_t)(I) * SR_STEP;               \
        const signed char* pb_ = Bbase + (size_t)kc_ * QR_KC +                \
                                 (kh_ * 34 + kw_) * 64;                       \
        GLD(fa[PAR][0], pa_);                                                 \
        GLD(fa[PAR][1], pa_ + 1024);                                          \
        GLD(fb[PAR][0], pb_ + bOff[0]);                                       \
        GLD(fb[PAR][1], pb_ + bOff[1]);                                       \
        GLD(fb[PAR][2], pb_ + bOff[2]);                                       \
        GLD(fb[PAR][3], pb_ + bOff[3]);                                       \
    } while (0)

#define MFMA8(PAR)                                                            \
    do {                                                                      \
        _Pragma("unroll")                                                     \
        for (int m = 0; m < 2; ++m)                                           \
            _Pragma("unroll")                                                 \
            for (int nn = 0; nn < 4; ++nn)                                    \
                acc[m][nn] = __builtin_amdgcn_mfma_i32_16x16x64_i8(           \
                    fa[PAR][m], fb[PAR][nn], acc[m][nn], 0, 0, 0);            \
    } while (0)

    LOADS(0, 0);
    LOADS(1, 1);
#pragma unroll
    for (int i = 0; i < 36; ++i) {
        if (i < 35) asm volatile("s_waitcnt vmcnt(6)" ::: "memory");
        else        asm volatile("s_waitcnt vmcnt(0)" ::: "memory");
        __builtin_amdgcn_sched_barrier(0);
        MFMA8(i & 1);
        if (i + 2 < 36) LOADS(i + 2, i & 1);
    }
#undef GLD
#undef LOADS
#undef MFMA8

    // D layout: col = l15 (pixel), row = kg*4 + r (o within 16)
    float psum = 0.f;
#pragma unroll
    for (int m = 0; m < 2; ++m) {
#pragma unroll
        for (int r = 0; r < 4; ++r) {
            int oLoc = oW + m * 16 + kg * 4 + r;  // 0..63
            int o = ob * 64 + oLoc;
            float al = sAl[oLoc];
            float inv = 0.f, bb = 0.f;
            if (FUSE) { inv = sInvS[oLoc]; bb = sBS[oLoc]; }
            const float* rp = resid + (size_t)n * 262144 + (size_t)o * 1024;
            float* op = out + (size_t)n * 262144 + (size_t)o * 1024;
#pragma unroll
            for (int nn = 0; nn < 4; ++nn) {
                float h = rp[pL[nn]] + al * (float)acc[m][nn][r];
                op[pL[nn]] = h;
                if (FUSE) psum += fabsf(h * inv + bb);
            }
        }
    }
    if (FUSE) {
        red[tid] = psum;
        __syncthreads();
        for (int off = 128; off > 0; off >>= 1) {
            if (tid < off) red[tid] += red[tid + off];
            __syncthreads();
        }
        if (tid == 0) partials[wg] = red[0];
    }
}

// ---------------------------------------------------------------------------
extern "C" void kernel_launch(void* const* d_in, const int* in_sizes, int n_in,
                              void* d_out, int out_size, void* d_ws, size_t ws_size,
                              hipStream_t stream) {
    (void)in_sizes; (void)n_in; (void)out_size; (void)ws_size;
    const float* x  = (const float*)d_in[0];
    const float* w1 = (const float*)d_in[1];
    const float* w2 = (const float*)d_in[2];
    const float* g1 = (const float*)d_in[3];
    const float* b1 = (const float*)d_in[4];
    const float* m1 = (const float*)d_in[5];
    const float* v1 = (const float*)d_in[6];
    const float* g2 = (const float*)d_in[7];
    const float* b2 = (const float*)d_in[8];
    const float* m2 = (const float*)d_in[9];
    const float* v2 = (const float*)d_in[10];
    float* out = (float*)d_out;
    char* ws = (char*)d_ws;

    float* delta1 = (float*)(ws + 0);
    float* delta2 = (float*)(ws + 4);
    float* red1   = (float*)(ws + 4096);       // 4096 floats
    float* redc   = (float*)(ws + 20480);      // 1024 floats
    float* alpha1 = (float*)(ws + 28672);
    float* alpha2 = (float*)(ws + 29696);
    signed char* Sr1 = (signed char*)(ws + ((size_t)1 << 20));
    signed char* Sr2 = (signed char*)(ws + ((size_t)2 << 20));
    signed char* qr1 = (signed char*)(ws + ((size_t)4 << 20));   // 9.5 MB
    signed char* qr2 = (signed char*)(ws + ((size_t)16 << 20));  // 9.5 MB
    float* h         = (float*)(ws + ((size_t)28 << 20));        // 134 MB

    const float kScale = 0.7f / 8388608.0f;

    halo_zero_kernel<<<528, 256, 0, stream>>>(qr1, qr2);
    prep_w_kernel<<<256, 256, 0, stream>>>(w1, Sr1, alpha1);
    prep_w_kernel<<<256, 256, 0, stream>>>(w2, Sr2, alpha2);
    bnabs_reduce_kernel<<<4096, 256, 0, stream>>>(x, g1, b1, m1, v1, red1);
    finalize_delta_kernel<<<1, 256, 0, stream>>>(red1, 4096, kScale, delta1);
    quant_kernel<<<512, 256, 0, stream>>>(x, g1, b1, m1, v1, delta1, qr1);
    tbn_conv_kernel<true><<<1024, 256, 0, stream>>>(qr1, Sr1, alpha1, x, h,
                                                    g2, b2, m2, v2, redc);
    finalize_delta_kernel<<<1, 256, 0, stream>>>(redc, 1024, kScale, delta2);
    quant_kernel<<<512, 256, 0, stream>>>(h, g2, b2, m2, v2, delta2, qr2);
    tbn_conv_kernel<false><<<1024, 256, 0, stream>>>(qr2, Sr2, alpha2, h, out,
                                                     nullptr, nullptr, nullptr,
                                                     nullptr, nullptr);
}

// Round 7
// 133.363 us; speedup vs baseline: 1.1926x; 1.1926x over previous
//
#include <hip/hip_runtime.h>

#define BN_EPS 1e-5f
#define QR_IMG   73984      // 34*34*64 bytes per (kc, image)
#define QR_KC    2367488    // 32 * QR_IMG
#define SR_STEP  16384      // per (t,kc): 256 o * 64B

typedef __attribute__((ext_vector_type(4))) int int32x4;

// ---------------------------------------------------------------------------
// Weight prep: alpha[o] = mean|w[o]| ; Sr[(t*4+kc)*256 + o][64] = sign i8.
// ---------------------------------------------------------------------------
__global__ void prep_w_kernel(const float* __restrict__ w,
                              signed char* __restrict__ Sr,
                              float* __restrict__ alpha) {
    int o = blockIdx.x;   // 256
    int c = threadIdx.x;  // 256
    const float* wp = w + (o * 256 + c) * 9;
    float s = 0.f;
    __shared__ __align__(16) signed char lsg[9][256];
    __shared__ float red[256];
#pragma unroll
    for (int j = 0; j < 9; ++j) {
        float v = wp[j];
        s += fabsf(v);
        lsg[j][c] = v > 0.f ? 1 : (v < 0.f ? -1 : 0);
    }
    red[c] = s;
    __syncthreads();
    for (int off = 128; off > 0; off >>= 1) {
        if (c < off) red[c] += red[c + off];
        __syncthreads();
    }
    if (c == 0) alpha[o] = red[0] / 2304.0f;
    if (c < 144) {
        int t = c / 16, u = c % 16;
        int c0 = u * 16;
        int kc = c0 >> 6, cb = c0 & 63;
        int32x4 v = *(const int32x4*)(&lsg[t][c0]);
        *(int32x4*)(Sr + (size_t)((t * 4 + kc) * 256 + o) * 64 + cb) = v;
    }
}

// ---------------------------------------------------------------------------
// Zero halo slots of both q buffers: border (y,x) of each [34][34] plane.
// 2 buf * 4 kc * 32 n * 132 slots * 4 sub = 135168 threads = 528 * 256.
// ---------------------------------------------------------------------------
__global__ void halo_zero_kernel(signed char* __restrict__ qr1,
                                 signed char* __restrict__ qr2) {
    int idx = blockIdx.x * 256 + threadIdx.x;
    int sub = idx & 3;
    int rest = idx >> 2;        // 33792
    int s = rest % 132;
    int r2 = rest / 132;        // 0..255 = 2 buf * 4 kc * 32 n
    int n = r2 & 31;
    int kc = (r2 >> 5) & 3;
    int b = r2 >> 7;
    int r, cc;
    if (s < 34)       { r = 0;        cc = s; }
    else if (s < 68)  { r = 33;       cc = s - 34; }
    else if (s < 100) { r = s - 67;   cc = 0; }
    else              { r = s - 99;   cc = 33; }
    signed char* p = (b ? qr2 : qr1) + (size_t)kc * QR_KC + (size_t)n * QR_IMG +
                     (size_t)(r * 34 + cc) * 64 + sub * 16;
    int32x4 z; z[0] = 0; z[1] = 0; z[2] = 0; z[3] = 0;
    *(int32x4*)p = z;
}

// ---------------------------------------------------------------------------
// partials[bid] = block-sum of |bn1(x)| (deterministic tree).
// ---------------------------------------------------------------------------
__global__ void bnabs_reduce_kernel(const float* __restrict__ x,
                                    const float* __restrict__ gamma,
                                    const float* __restrict__ beta,
                                    const float* __restrict__ mean,
                                    const float* __restrict__ var,
                                    float* __restrict__ partials) {
    int tid = blockIdx.x * blockDim.x + threadIdx.x;
    int nthreads = gridDim.x * blockDim.x;
    const float4* x4 = (const float4*)x;
    float s = 0.f;
    for (int i = tid; i < 2097152; i += nthreads) {
        int c = (i >> 8) & 255;
        float inv = gamma[c] * rsqrtf(var[c] + BN_EPS);
        float b = beta[c] - mean[c] * inv;
        float4 v = x4[i];
        s += fabsf(v.x * inv + b) + fabsf(v.y * inv + b) +
             fabsf(v.z * inv + b) + fabsf(v.w * inv + b);
    }
    __shared__ float red[256];
    red[threadIdx.x] = s;
    __syncthreads();
    for (int off = 128; off > 0; off >>= 1) {
        if (threadIdx.x < off) red[threadIdx.x] += red[threadIdx.x + off];
        __syncthreads();
    }
    if (threadIdx.x == 0) partials[blockIdx.x] = red[0];
}

__global__ void finalize_delta_kernel(const float* __restrict__ partials, int n,
                                      float scale, float* __restrict__ out) {
    __shared__ float red[256];
    float s = 0.f;
    for (int i = threadIdx.x; i < n; i += 256) s += partials[i];
    red[threadIdx.x] = s;
    __syncthreads();
    for (int off = 128; off > 0; off >>= 1) {
        if (threadIdx.x < off) red[threadIdx.x] += red[threadIdx.x + off];
        __syncthreads();
    }
    if (threadIdx.x == 0) *out = red[0] * scale;
}

// ---------------------------------------------------------------------------
// Quantize into k-chunk-major padded layout:
// qr[kc][n][y+1][x+1][64] i8 in {-1,0,+1}; halo untouched (zeroed once).
// ---------------------------------------------------------------------------
__global__ __launch_bounds__(256) void quant_kernel(
    const float* __restrict__ src,
    const float* __restrict__ gamma, const float* __restrict__ beta,
    const float* __restrict__ mean, const float* __restrict__ var,
    const float* __restrict__ deltaPtr, signed char* __restrict__ qr) {
    __shared__ float sInv[256], sB[256];
    int tid = threadIdx.x;
    {
        float inv = gamma[tid] * rsqrtf(var[tid] + BN_EPS);
        sInv[tid] = inv;
        sB[tid] = beta[tid] - mean[tid] * inv;
    }
    __syncthreads();
    int bid = blockIdx.x;          // 512 = 32 n * 16 pblk
    int n = bid >> 4;
    int p0 = (bid & 15) * 64;
    int l = tid & 63, wv = tid >> 6;   // wv == kc
    int p = p0 + l;
    int y = p >> 5, x = p & 31;
    float delta = *deltaPtr;
    const float* sp = src + (size_t)n * 262144 + p;
    signed char* qp = qr + (size_t)wv * QR_KC + (size_t)n * QR_IMG +
                      (size_t)((y + 1) * 34 + (x + 1)) * 64;
#pragma unroll
    for (int kg = 0; kg < 4; ++kg) {
        int w4[4];
#pragma unroll
        for (int d = 0; d < 4; ++d) {
            int wrd = 0;
#pragma unroll
            for (int j = 0; j < 4; ++j) {
                int c = wv * 64 + kg * 16 + d * 4 + j;
                float s = sp[c * 1024] * sInv[c] + sB[c];
                int qv = s > delta ? 1 : (s < -delta ? -1 : 0);
                wrd |= (qv & 255) << (8 * j);
            }
            w4[d] = wrd;
        }
        int32x4 vv;
        vv[0] = w4[0]; vv[1] = w4[1]; vv[2] = w4[2]; vv[3] = w4[3];
        *(int32x4*)(qp + kg * 16) = vv;
    }
}

// ---------------------------------------------------------------------------
// TBN conv: i8 MFMA 16x16x64. 512 blocks x 4 waves; block 128o x 128px,
// wave 64o x 64px. NO LDS staging, NO main-loop barriers: 3-step-deep
// volatile-asm register ring from L2-hot buffers, counted vmcnt(16).
// Issue->wait distance = 2 full MFMA bursts (~650 cyc) > L2 latency.
// ---------------------------------------------------------------------------
template <bool FUSE>
__global__ __launch_bounds__(256, 2) void tbn_conv_kernel(
    const signed char* __restrict__ qr,   // [4][32][34][34][64] i8
    const signed char* __restrict__ Sr,   // [36][256][64] i8 ([t*4+kc] major)
    const float* __restrict__ alpha,      // [256]
    const float* __restrict__ resid,      // [32][256][1024] f32
    float* __restrict__ out,              // [32][256][1024] f32
    const float* __restrict__ gamma, const float* __restrict__ beta,
    const float* __restrict__ mean, const float* __restrict__ var,
    float* __restrict__ partials) {
    int bid = blockIdx.x;
    int wg = (bid & 7) * 64 + (bid >> 3);  // bijective, 512 % 8 == 0
    int n = wg >> 4;
    int pb = (wg >> 1) & 7;
    int ob = wg & 1;
    int tid = threadIdx.x, lane = tid & 63, wid = tid >> 6;
    int l15 = lane & 15, kg = lane >> 4;

    __shared__ float sAl[128], sInvS[128], sBS[128];
    __shared__ float red[256];
    if (tid < 128) {
        int o = ob * 128 + tid;
        sAl[tid] = alpha[o];
        if (FUSE) {
            float inv = gamma[o] * rsqrtf(var[o] + BN_EPS);
            sInvS[tid] = inv;
            sBS[tid] = beta[o] - mean[o] * inv;
        }
    }
    __syncthreads();

    int oW = (wid >> 1) * 64, pW = (wid & 1) * 64;
    int o0 = ob * 128 + oW;

    // A lane base: frag m at +m*1024 within a (t,kc) slab
    const signed char* Abase = Sr + (size_t)(o0 + l15) * 64 + kg * 16;
    const signed char* Bbase = qr + (size_t)n * QR_IMG + kg * 16;
    int bOff[4], pL[4];
#pragma unroll
    for (int nn = 0; nn < 4; ++nn) {
        int p = pb * 128 + pW + nn * 16 + l15;
        pL[nn] = p;
        int pt = p - l15;               // tile origin, multiple of 16
        int y = pt >> 5, x = pt & 31;   // all 16 lanes share y
        bOff[nn] = ((y + 1) * 34 + (x + 1) + l15) * 64;
    }

    int32x4 acc[4][4];
#pragma unroll
    for (int m = 0; m < 4; ++m)
#pragma unroll
        for (int nn = 0; nn < 4; ++nn) {
            acc[m][nn][0] = 0; acc[m][nn][1] = 0;
            acc[m][nn][2] = 0; acc[m][nn][3] = 0;
        }

    int32x4 fa[3][4], fb[3][4];

#define GLD(D, P) \
    asm volatile("global_load_dwordx4 %0, %1, off" : "=v"(D) : "v"(P))

#define LOADS(I)                                                              \
    do {                                                                      \
        const int t_ = (I) >> 2, kc_ = (I) & 3;                               \
        const int kh_ = t_ / 3 - 1, kw_ = t_ % 3 - 1;                         \
        const signed char* pa_ = Abase + (size_t)(I) * SR_STEP;               \
        const signed char* pb_ = Bbase + (size_t)kc_ * QR_KC +                \
                                 (kh_ * 34 + kw_) * 64;                       \
        GLD(fa[(I) % 3][0], pa_);                                             \
        GLD(fa[(I) % 3][1], pa_ + 1024);                                      \
        GLD(fa[(I) % 3][2], pa_ + 2048);                                      \
        GLD(fa[(I) % 3][3], pa_ + 3072);                                      \
        GLD(fb[(I) % 3][0], pb_ + bOff[0]);                                   \
        GLD(fb[(I) % 3][1], pb_ + bOff[1]);                                   \
        GLD(fb[(I) % 3][2], pb_ + bOff[2]);                                   \
        GLD(fb[(I) % 3][3], pb_ + bOff[3]);                                   \
    } while (0)

#define MFMA16(I)                                                             \
    do {                                                                      \
        _Pragma("unroll")                                                     \
        for (int m = 0; m < 4; ++m)                                           \
            _Pragma("unroll")                                                 \
            for (int nn = 0; nn < 4; ++nn)                                    \
                acc[m][nn] = __builtin_amdgcn_mfma_i32_16x16x64_i8(           \
                    fa[(I) % 3][m], fb[(I) % 3][nn], acc[m][nn], 0, 0, 0);    \
    } while (0)

    LOADS(0); LOADS(1); LOADS(2);
#pragma unroll
    for (int i = 0; i < 36; ++i) {
        // steady state: 3 steps (24 loads) outstanding; retire step i's 8.
        if (i < 34)       asm volatile("s_waitcnt vmcnt(16)" ::: "memory");
        else if (i == 34) asm volatile("s_waitcnt vmcnt(8)"  ::: "memory");
        else              asm volatile("s_waitcnt vmcnt(0)"  ::: "memory");
        __builtin_amdgcn_sched_barrier(0);
        MFMA16(i);
        if (i + 3 < 36) LOADS(i + 3);
    }
#undef GLD
#undef LOADS
#undef MFMA16

    // D layout: col = l15 (pixel), row = kg*4 + r (o within 16)
    float psum = 0.f;
#pragma unroll
    for (int m = 0; m < 4; ++m) {
#pragma unroll
        for (int r = 0; r < 4; ++r) {
            int oLoc = oW + m * 16 + kg * 4 + r;  // 0..127
            int o = ob * 128 + oLoc;
            float al = sAl[oLoc];
            float inv = 0.f, bb = 0.f;
            if (FUSE) { inv = sInvS[oLoc]; bb = sBS[oLoc]; }
            const float* rp = resid + (size_t)n * 262144 + (size_t)o * 1024;
            float* op = out + (size_t)n * 262144 + (size_t)o * 1024;
#pragma unroll
            for (int nn = 0; nn < 4; ++nn) {
                float h = rp[pL[nn]] + al * (float)acc[m][nn][r];
                op[pL[nn]] = h;
                if (FUSE) psum += fabsf(h * inv + bb);
            }
        }
    }
    if (FUSE) {
        red[tid] = psum;
        __syncthreads();
        for (int off = 128; off > 0; off >>= 1) {
            if (tid < off) red[tid] += red[tid + off];
            __syncthreads();
        }
        if (tid == 0) partials[wg] = red[0];
    }
}

// ---------------------------------------------------------------------------
extern "C" void kernel_launch(void* const* d_in, const int* in_sizes, int n_in,
                              void* d_out, int out_size, void* d_ws, size_t ws_size,
                              hipStream_t stream) {
    (void)in_sizes; (void)n_in; (void)out_size; (void)ws_size;
    const float* x  = (const float*)d_in[0];
    const float* w1 = (const float*)d_in[1];
    const float* w2 = (const float*)d_in[2];
    const float* g1 = (const float*)d_in[3];
    const float* b1 = (const float*)d_in[4];
    const float* m1 = (const float*)d_in[5];
    const float* v1 = (const float*)d_in[6];
    const float* g2 = (const float*)d_in[7];
    const float* b2 = (const float*)d_in[8];
    const float* m2 = (const float*)d_in[9];
    const float* v2 = (const float*)d_in[10];
    float* out = (float*)d_out;
    char* ws = (char*)d_ws;

    float* delta1 = (float*)(ws + 0);
    float* delta2 = (float*)(ws + 4);
    float* red1   = (float*)(ws + 4096);       // 4096 floats
    float* redc   = (float*)(ws + 20480);      // 512 floats
    float* alpha1 = (float*)(ws + 24576);
    float* alpha2 = (float*)(ws + 25600);
    signed char* Sr1 = (signed char*)(ws + ((size_t)1 << 20));
    signed char* Sr2 = (signed char*)(ws + ((size_t)2 << 20));
    signed char* qr1 = (signed char*)(ws + ((size_t)4 << 20));   // 9.5 MB
    signed char* qr2 = (signed char*)(ws + ((size_t)16 << 20));  // 9.5 MB
    float* h         = (float*)(ws + ((size_t)28 << 20));        // 134 MB

    const float kScale = 0.7f / 8388608.0f;

    halo_zero_kernel<<<528, 256, 0, stream>>>(qr1, qr2);
    prep_w_kernel<<<256, 256, 0, stream>>>(w1, Sr1, alpha1);
    prep_w_kernel<<<256, 256, 0, stream>>>(w2, Sr2, alpha2);
    bnabs_reduce_kernel<<<4096, 256, 0, stream>>>(x, g1, b1, m1, v1, red1);
    finalize_delta_kernel<<<1, 256, 0, stream>>>(red1, 4096, kScale, delta1);
    quant_kernel<<<512, 256, 0, stream>>>(x, g1, b1, m1, v1, delta1, qr1);
    tbn_conv_kernel<true><<<512, 256, 0, stream>>>(qr1, Sr1, alpha1, x, h,
                                                   g2, b2, m2, v2, redc);
    finalize_delta_kernel<<<1, 256, 0, stream>>>(redc, 512, kScale, delta2);
    quant_kernel<<<512, 256, 0, stream>>>(h, g2, b2, m2, v2, delta2, qr2);
    tbn_conv_kernel<false><<<512, 256, 0, stream>>>(qr2, Sr2, alpha2, h, out,
                                                    nullptr, nullptr, nullptr,
                                                    nullptr, nullptr);
}

// Round 8
// 97.069 us; speedup vs baseline: 1.6385x; 1.3739x over previous
//
#include <hip/hip_runtime.h>

#define BN_EPS 1e-5f
#define QR_IMG   73984      // 34*34*64 bytes per (kc, image)
#define QR_KC    2367488    // 32 * QR_IMG
#define QR_ROWB  2176       // 34 slots * 64B
#define SR_STEP  16384      // per (t,kc): 256 o * 64B

typedef __attribute__((ext_vector_type(4))) int int32x4;

// ---------------------------------------------------------------------------
// Weight prep: alpha[o] = mean|w[o]| ; Sr[(t*4+kc)*256 + o][64] = sign i8.
// ---------------------------------------------------------------------------
__global__ void prep_w_kernel(const float* __restrict__ w,
                              signed char* __restrict__ Sr,
                              float* __restrict__ alpha) {
    int o = blockIdx.x;   // 256
    int c = threadIdx.x;  // 256
    const float* wp = w + (o * 256 + c) * 9;
    float s = 0.f;
    __shared__ __align__(16) signed char lsg[9][256];
    __shared__ float red[256];
#pragma unroll
    for (int j = 0; j < 9; ++j) {
        float v = wp[j];
        s += fabsf(v);
        lsg[j][c] = v > 0.f ? 1 : (v < 0.f ? -1 : 0);
    }
    red[c] = s;
    __syncthreads();
    for (int off = 128; off > 0; off >>= 1) {
        if (c < off) red[c] += red[c + off];
        __syncthreads();
    }
    if (c == 0) alpha[o] = red[0] / 2304.0f;
    if (c < 144) {
        int t = c / 16, u = c % 16;
        int c0 = u * 16;
        int kc = c0 >> 6, cb = c0 & 63;
        int32x4 v = *(const int32x4*)(&lsg[t][c0]);
        *(int32x4*)(Sr + (size_t)((t * 4 + kc) * 256 + o) * 64 + cb) = v;
    }
}

// ---------------------------------------------------------------------------
// Zero halo slots of both q buffers: border of each [34][34] plane.
// ---------------------------------------------------------------------------
__global__ void halo_zero_kernel(signed char* __restrict__ qr1,
                                 signed char* __restrict__ qr2) {
    int idx = blockIdx.x * 256 + threadIdx.x;
    int sub = idx & 3;
    int rest = idx >> 2;        // 33792
    int s = rest % 132;
    int r2 = rest / 132;        // 0..255 = 2 buf * 4 kc * 32 n
    int n = r2 & 31;
    int kc = (r2 >> 5) & 3;
    int b = r2 >> 7;
    int r, cc;
    if (s < 34)       { r = 0;        cc = s; }
    else if (s < 68)  { r = 33;       cc = s - 34; }
    else if (s < 100) { r = s - 67;   cc = 0; }
    else              { r = s - 99;   cc = 33; }
    signed char* p = (b ? qr2 : qr1) + (size_t)kc * QR_KC + (size_t)n * QR_IMG +
                     (size_t)(r * 34 + cc) * 64 + sub * 16;
    int32x4 z; z[0] = 0; z[1] = 0; z[2] = 0; z[3] = 0;
    *(int32x4*)p = z;
}

// ---------------------------------------------------------------------------
// partials[bid] = block-sum of |bn1(x)| (deterministic tree).
// ---------------------------------------------------------------------------
__global__ void bnabs_reduce_kernel(const float* __restrict__ x,
                                    const float* __restrict__ gamma,
                                    const float* __restrict__ beta,
                                    const float* __restrict__ mean,
                                    const float* __restrict__ var,
                                    float* __restrict__ partials) {
    int tid = blockIdx.x * blockDim.x + threadIdx.x;
    int nthreads = gridDim.x * blockDim.x;
    const float4* x4 = (const float4*)x;
    float s = 0.f;
    for (int i = tid; i < 2097152; i += nthreads) {
        int c = (i >> 8) & 255;
        float inv = gamma[c] * rsqrtf(var[c] + BN_EPS);
        float b = beta[c] - mean[c] * inv;
        float4 v = x4[i];
        s += fabsf(v.x * inv + b) + fabsf(v.y * inv + b) +
             fabsf(v.z * inv + b) + fabsf(v.w * inv + b);
    }
    __shared__ float red[256];
    red[threadIdx.x] = s;
    __syncthreads();
    for (int off = 128; off > 0; off >>= 1) {
        if (threadIdx.x < off) red[threadIdx.x] += red[threadIdx.x + off];
        __syncthreads();
    }
    if (threadIdx.x == 0) partials[blockIdx.x] = red[0];
}

__global__ void finalize_delta_kernel(const float* __restrict__ partials, int n,
                                      float scale, float* __restrict__ out) {
    __shared__ float red[256];
    float s = 0.f;
    for (int i = threadIdx.x; i < n; i += 256) s += partials[i];
    red[threadIdx.x] = s;
    __syncthreads();
    for (int off = 128; off > 0; off >>= 1) {
        if (threadIdx.x < off) red[threadIdx.x] += red[threadIdx.x + off];
        __syncthreads();
    }
    if (threadIdx.x == 0) *out = red[0] * scale;
}

// ---------------------------------------------------------------------------
// Quantize into k-chunk-major padded layout:
// qr[kc][n][y+1][x+1][64] i8 in {-1,0,+1}; halo untouched (zeroed once).
// ---------------------------------------------------------------------------
__global__ __launch_bounds__(256) void quant_kernel(
    const float* __restrict__ src,
    const float* __restrict__ gamma, const float* __restrict__ beta,
    const float* __restrict__ mean, const float* __restrict__ var,
    const float* __restrict__ deltaPtr, signed char* __restrict__ qr) {
    __shared__ float sInv[256], sB[256];
    int tid = threadIdx.x;
    {
        float inv = gamma[tid] * rsqrtf(var[tid] + BN_EPS);
        sInv[tid] = inv;
        sB[tid] = beta[tid] - mean[tid] * inv;
    }
    __syncthreads();
    int bid = blockIdx.x;          // 512 = 32 n * 16 pblk
    int n = bid >> 4;
    int p0 = (bid & 15) * 64;
    int l = tid & 63, wv = tid >> 6;   // wv == kc
    int p = p0 + l;
    int y = p >> 5, x = p & 31;
    float delta = *deltaPtr;
    const float* sp = src + (size_t)n * 262144 + p;
    signed char* qp = qr + (size_t)wv * QR_KC + (size_t)n * QR_IMG +
                      (size_t)((y + 1) * 34 + (x + 1)) * 64;
#pragma unroll
    for (int kg = 0; kg < 4; ++kg) {
        int w4[4];
#pragma unroll
        for (int d = 0; d < 4; ++d) {
            int wrd = 0;
#pragma unroll
            for (int j = 0; j < 4; ++j) {
                int c = wv * 64 + kg * 16 + d * 4 + j;
                float s = sp[c * 1024] * sInv[c] + sB[c];
                int qv = s > delta ? 1 : (s < -delta ? -1 : 0);
                wrd |= (qv & 255) << (8 * j);
            }
            w4[d] = wrd;
        }
        int32x4 vv;
        vv[0] = w4[0]; vv[1] = w4[1]; vv[2] = w4[2]; vv[3] = w4[3];
        *(int32x4*)(qp + kg * 16) = vv;
    }
}

// ---------------------------------------------------------------------------
// TBN conv: i8 MFMA 16x16x64. 512 blocks x 4 waves; block 128o x 128px,
// wave 32o x 128px (A unique/wave, B block-shared from LDS, 9-tap reuse).
// B reg-staged into swizzled LDS per kc (T14 split; raw lgkm-only barriers,
// no vmcnt drain). A from L2-hot Sr via 3-deep asm ring, counted vmcnt.
// ---------------------------------------------------------------------------
template <bool FUSE>
__global__ __launch_bounds__(256, 2) void tbn_conv_kernel(
    const signed char* __restrict__ qr,   // [4][32][34][34][64] i8
    const signed char* __restrict__ Sr,   // [t*4+kc][256][64] i8
    const float* __restrict__ alpha,      // [256]
    const float* __restrict__ resid,      // [32][256][1024] f32
    float* __restrict__ out,              // [32][256][1024] f32
    const float* __restrict__ gamma, const float* __restrict__ beta,
    const float* __restrict__ mean, const float* __restrict__ var,
    float* __restrict__ partials) {
    __shared__ __align__(16) signed char Bl[13056];  // [6 rows][34 slots][64] swz
    __shared__ float sAl[128], sInvS[128], sBS[128];
    __shared__ float red[256];

    int bid = blockIdx.x;
    int wg = (bid & 7) * 64 + (bid >> 3);  // bijective, 512 % 8 == 0
    int n = wg >> 4;
    int pb = (wg >> 1) & 7;
    int ob = wg & 1;
    int tid = threadIdx.x, lane = tid & 63, wid = tid >> 6;
    int l15 = lane & 15, kg = lane >> 4;

    if (tid < 128) {
        int o = ob * 128 + tid;
        sAl[tid] = alpha[o];
        if (FUSE) {
            float inv = gamma[o] * rsqrtf(var[o] + BN_EPS);
            sInvS[tid] = inv;
            sBS[tid] = beta[o] - mean[o] * inv;
        }
    }
    __syncthreads();

    int o0 = ob * 128 + wid * 32;
    int y0 = pb * 4;  // first padded row of the 6-row B window

    const signed char* Abase = Sr + (size_t)(o0 + l15) * 64 + kg * 16;
    const signed char* gsrcBase = qr + (size_t)n * QR_IMG + (size_t)y0 * QR_ROWB;

    // stage offsets: 816 x 16B pieces, 4 per thread (clamped dup at tail)
    int stSrc[4], stDst[4];
#pragma unroll
    for (int k = 0; k < 4; ++k) {
        int idx = tid + 256 * k; if (idx > 815) idx = 815;
        int byte = idx * 16;
        int row = byte / 2176;
        int rem = byte - row * 2176;
        int slot = rem >> 6;
        int kgp = (rem >> 4) & 3;
        stSrc[k] = byte;
        stDst[k] = row * 2176 + slot * 64 + (((kgp + (slot >> 1)) & 3) << 4);
    }

    int sEven = l15 + 1;   // slot base, even nn (add kw at use)
    int sOdd  = l15 + 17;  // slot base, odd nn

    int32x4 acc[2][8];
#pragma unroll
    for (int m = 0; m < 2; ++m)
#pragma unroll
        for (int nn = 0; nn < 8; ++nn) {
            acc[m][nn][0] = 0; acc[m][nn][1] = 0;
            acc[m][nn][2] = 0; acc[m][nn][3] = 0;
        }

    int32x4 fa[3][2], fb[2][8], stReg[4];

#define GLD(D, P) \
    asm volatile("global_load_dwordx4 %0, %1, off" : "=v"(D) : "v"(P))
#define SLAB(I) ((((I) % 9) * 4) + ((I) / 9))
#define LOADA(I)                                                              \
    do {                                                                      \
        const signed char* pa_ = Abase + (size_t)SLAB(I) * SR_STEP;           \
        GLD(fa[(I) % 3][0], pa_);                                             \
        GLD(fa[(I) % 3][1], pa_ + 1024);                                      \
    } while (0)
#define STAGE_ISSUE(KC)                                                       \
    do {                                                                      \
        const signed char* g_ = gsrcBase + (size_t)(KC) * QR_KC;              \
        GLD(stReg[0], g_ + stSrc[0]);                                         \
        GLD(stReg[1], g_ + stSrc[1]);                                         \
        GLD(stReg[2], g_ + stSrc[2]);                                         \
        GLD(stReg[3], g_ + stSrc[3]);                                         \
    } while (0)
#define STAGE_WRITE()                                                         \
    do {                                                                      \
        *(int32x4*)(&Bl[stDst[0]]) = stReg[0];                                \
        *(int32x4*)(&Bl[stDst[1]]) = stReg[1];                                \
        *(int32x4*)(&Bl[stDst[2]]) = stReg[2];                                \
        *(int32x4*)(&Bl[stDst[3]]) = stReg[3];                                \
    } while (0)
#define LOADB(T, BUF)                                                         \
    do {                                                                      \
        _Pragma("unroll")                                                     \
        for (int nn = 0; nn < 8; ++nn) {                                      \
            const int kh_ = (T) / 3 - 1, kw_ = (T) % 3 - 1;                   \
            const int row_ = (nn >> 1) + 1 + kh_;                             \
            int slot_ = ((nn & 1) ? sOdd : sEven) + kw_;                      \
            int off_ = row_ * 2176 + slot_ * 64 +                             \
                       (((kg + (slot_ >> 1)) & 3) << 4);                      \
            fb[BUF][nn] = *(const int32x4*)(&Bl[off_]);                       \
        }                                                                     \
    } while (0)
#define MFMA16(I, BUF)                                                        \
    do {                                                                      \
        _Pragma("unroll")                                                     \
        for (int m = 0; m < 2; ++m)                                           \
            _Pragma("unroll")                                                 \
            for (int nn = 0; nn < 8; ++nn)                                    \
                acc[m][nn] = __builtin_amdgcn_mfma_i32_16x16x64_i8(           \
                    fa[(I) % 3][m], fb[BUF][nn], acc[m][nn], 0, 0, 0);        \
    } while (0)
#define WAITV(N)                                                              \
    do { asm volatile("s_waitcnt vmcnt(" #N ")" ::: "memory");                \
         __builtin_amdgcn_sched_barrier(0); } while (0)
#define WAITL()                                                               \
    do { asm volatile("s_waitcnt lgkmcnt(0)" ::: "memory");                   \
         __builtin_amdgcn_sched_barrier(0); } while (0)
#define BAR()                                                                 \
    do { __builtin_amdgcn_s_barrier();                                        \
         __builtin_amdgcn_sched_barrier(0); } while (0)

    // prologue: stage kc=0, prime A ring, publish Bl
    STAGE_ISSUE(0);
    LOADA(0); LOADA(1); LOADA(2);
    WAITV(6);            // retires the 4 stage loads (A 0..2 may be in flight)
    STAGE_WRITE();
    WAITL();
    BAR();
    LOADB(0, 0);

#pragma unroll
    for (int i = 0; i < 36; ++i) {
        const int kc = i / 9, t = i % 9;
        // exact FIFO counts: retire A(i); newer = A(i+1),A(i+2)(+stage if hot)
        if (i == 1 || i == 2 || i == 10 || i == 11 || i == 19 || i == 20) {
            WAITV(8);
        } else if (i == 34) { WAITV(2); }
        else if (i == 35)   { WAITV(0); }
        else                { WAITV(4); }
        if (t == 0 && kc < 3) STAGE_ISSUE(kc + 1);
        if (t < 8) LOADB(t + 1, (t + 1) & 1);
        MFMA16(i, t & 1);
        if (i + 3 <= 35) LOADA(i + 3);
        if (t == 8 && kc < 3) {
            WAITL();
            BAR();            // all waves done reading Bl (lgkm only, no vmcnt)
            STAGE_WRITE();    // stage regs retired since t>=5's waits
            WAITL();
            BAR();            // writes visible
            LOADB(0, 0);
        }
    }
#undef GLD
#undef SLAB
#undef LOADA
#undef STAGE_ISSUE
#undef STAGE_WRITE
#undef LOADB
#undef MFMA16
#undef WAITV
#undef WAITL
#undef BAR

    // D layout: col = l15 (pixel), row = kg*4 + r (o within 16)
    float psum = 0.f;
#pragma unroll
    for (int m = 0; m < 2; ++m) {
#pragma unroll
        for (int r = 0; r < 4; ++r) {
            int oLoc = wid * 32 + m * 16 + kg * 4 + r;  // 0..127
            int o = ob * 128 + oLoc;
            float al = sAl[oLoc];
            float inv = 0.f, bb = 0.f;
            if (FUSE) { inv = sInvS[oLoc]; bb = sBS[oLoc]; }
            const float* rp = resid + (size_t)n * 262144 + (size_t)o * 1024;
            float* op = out + (size_t)n * 262144 + (size_t)o * 1024;
#pragma unroll
            for (int nn = 0; nn < 8; ++nn) {
                int p = pb * 128 + nn * 16 + l15;
                float hv = rp[p] + al * (float)acc[m][nn][r];
                op[p] = hv;
                if (FUSE) psum += fabsf(hv * inv + bb);
            }
        }
    }
    if (FUSE) {
        red[tid] = psum;
        __syncthreads();
        for (int off = 128; off > 0; off >>= 1) {
            if (tid < off) red[tid] += red[tid + off];
            __syncthreads();
        }
        if (tid == 0) partials[wg] = red[0];
    }
}

// ---------------------------------------------------------------------------
extern "C" void kernel_launch(void* const* d_in, const int* in_sizes, int n_in,
                              void* d_out, int out_size, void* d_ws, size_t ws_size,
                              hipStream_t stream) {
    (void)in_sizes; (void)n_in; (void)out_size; (void)ws_size;
    const float* x  = (const float*)d_in[0];
    const float* w1 = (const float*)d_in[1];
    const float* w2 = (const float*)d_in[2];
    const float* g1 = (const float*)d_in[3];
    const float* b1 = (const float*)d_in[4];
    const float* m1 = (const float*)d_in[5];
    const float* v1 = (const float*)d_in[6];
    const float* g2 = (const float*)d_in[7];
    const float* b2 = (const float*)d_in[8];
    const float* m2 = (const float*)d_in[9];
    const float* v2 = (const float*)d_in[10];
    float* out = (float*)d_out;
    char* ws = (char*)d_ws;

    float* delta1 = (float*)(ws + 0);
    float* delta2 = (float*)(ws + 4);
    float* red1   = (float*)(ws + 4096);       // 4096 floats
    float* redc   = (float*)(ws + 20480);      // 512 floats
    float* alpha1 = (float*)(ws + 24576);
    float* alpha2 = (float*)(ws + 25600);
    signed char* Sr1 = (signed char*)(ws + ((size_t)1 << 20));
    signed char* Sr2 = (signed char*)(ws + ((size_t)2 << 20));
    signed char* qr1 = (signed char*)(ws + ((size_t)4 << 20));   // 9.5 MB
    signed char* qr2 = (signed char*)(ws + ((size_t)16 << 20));  // 9.5 MB
    float* h         = (float*)(ws + ((size_t)28 << 20));        // 134 MB

    const float kScale = 0.7f / 8388608.0f;

    halo_zero_kernel<<<528, 256, 0, stream>>>(qr1, qr2);
    prep_w_kernel<<<256, 256, 0, stream>>>(w1, Sr1, alpha1);
    prep_w_kernel<<<256, 256, 0, stream>>>(w2, Sr2, alpha2);
    bnabs_reduce_kernel<<<4096, 256, 0, stream>>>(x, g1, b1, m1, v1, red1);
    finalize_delta_kernel<<<1, 256, 0, stream>>>(red1, 4096, kScale, delta1);
    quant_kernel<<<512, 256, 0, stream>>>(x, g1, b1, m1, v1, delta1, qr1);
    tbn_conv_kernel<true><<<512, 256, 0, stream>>>(qr1, Sr1, alpha1, x, h,
                                                   g2, b2, m2, v2, redc);
    finalize_delta_kernel<<<1, 256, 0, stream>>>(redc, 512, kScale, delta2);
    quant_kernel<<<512, 256, 0, stream>>>(h, g2, b2, m2, v2, delta2, qr2);
    tbn_conv_kernel<false><<<512, 256, 0, stream>>>(qr2, Sr2, alpha2, h, out,
                                                    nullptr, nullptr, nullptr,
                                                    nullptr, nullptr);
}